// Round 14
// baseline (182.248 us; speedup 1.0000x reference)
//
#include <hip/hip_runtime.h>
#include <stdint.h>

#define BB 8
#define C  64
#define H  256
#define W  256
#define HW (H*W)
#define EPSV 1e-6f

typedef unsigned long long u64;
typedef float __attribute__((ext_vector_type(4))) f32x4;
typedef int __attribute__((ext_vector_type(4)))  v4i;

// ------- K1: merged stats ∥ pack via block-role split (R13 identical) -------
__global__ __launch_bounds__(256) void k_sp(const float* __restrict__ x,
                                            const float* __restrict__ bmove,
                                            float* __restrict__ sums /* [3][512] */,
                                            u64* __restrict__ packed) {
  __shared__ f32x4 lds4[64 * 33];
  __shared__ float red[4][3];
  int id = blockIdx.x;
  int q3 = id / 3;
  if (id - q3 * 3 == 0) {
    int bc = q3;
    float bm = bmove[bc & 63];
    const f32x4* p = (const f32x4*)(x + (size_t)bc * HW);
    int t = threadIdx.x;
    float s = 0.f, s2 = 0.f, sa = 0.f;
    #pragma unroll 8
    for (int k = 0; k < 64; ++k) {
      f32x4 v = p[(k << 8) | t];
      float a0 = v.x + bm, a1 = v.y + bm, a2 = v.z + bm, a3 = v.w + bm;
      s  += a0 + a1 + a2 + a3;
      s2 += a0*a0 + a1*a1 + a2*a2 + a3*a3;
      sa += fabsf(a0) + fabsf(a1) + fabsf(a2) + fabsf(a3);
    }
    #pragma unroll
    for (int off = 32; off > 0; off >>= 1) {
      s  += __shfl_down(s,  off, 64);
      s2 += __shfl_down(s2, off, 64);
      sa += __shfl_down(sa, off, 64);
    }
    int wid = t >> 6;
    if ((t & 63) == 0) { red[wid][0] = s; red[wid][1] = s2; red[wid][2] = sa; }
    __syncthreads();
    if (t == 0) {
      float S  = red[0][0] + red[1][0] + red[2][0] + red[3][0];
      float S2 = red[0][1] + red[1][1] + red[2][1] + red[3][1];
      float SA = red[0][2] + red[1][2] + red[2][2] + red[3][2];
      sums[bc] = S; sums[512 + bc] = S2; sums[1024 + bc] = SA;
    }
  } else {
    int blk = id - q3 - 1;
    int b   = blk >> 7;
    int rg  = blk & 127;
    int h0  = rg << 1;
    int tid = threadIdx.x;
    int wid = tid >> 6, lane = tid & 63;

    float bm = bmove[lane];
    int p4l = tid & 31;
    int cg  = tid >> 5;
    const size_t bbase = (size_t)b * C * HW;

    for (int tile = 0; tile < 4; ++tile) {
      int h  = h0 + (tile >> 1);
      int wb = (tile & 1) << 7;
      __syncthreads();
      #pragma unroll
      for (int cc = 0; cc < 8; ++cc) {
        int c = cg + (cc << 3);
        lds4[c * 33 + p4l] =
            *((const f32x4*)(x + bbase + (size_t)c * HW + h * W + wb) + p4l);
      }
      __syncthreads();
      u64* pdst = packed + ((size_t)(b * H + h)) * W + wb;
      #pragma unroll
      for (int k = 0; k < 8; ++k) {
        int p4i = (wid << 3) + k;
        f32x4 v = lds4[lane * 33 + p4i];
        u64 q0 = __ballot(v.x + bm > 0.f);
        u64 q1 = __ballot(v.y + bm > 0.f);
        u64 q2 = __ballot(v.z + bm > 0.f);
        u64 q3b = __ballot(v.w + bm > 0.f);
        u64 qa = (lane & 1) ? q1 : q0;
        u64 qb = (lane & 1) ? q3b : q2;
        u64 qq = (lane & 2) ? qb : qa;
        if (lane < 4) pdst[(p4i << 2) + lane] = qq;
      }
    }
  }
}

// -------- K2: gate + sumw + 16x16x64 A-fragment table -----------------------
__global__ __launch_bounds__(512) void k_gate(const float* __restrict__ sums,
                                              const float* __restrict__ w_conv,
                                              const float* __restrict__ w1d,
                                              float* __restrict__ alpha,
                                              float* __restrict__ sumw_g,
                                              char*  __restrict__ atab) {
  __shared__ float stA[512], stM[512], stS[512];
  __shared__ float swv[64];
  __shared__ float stap[64][9];
  int tid = threadIdx.x;

  // atab16: [oq(4)][tap(9)][lane(64)] x 16B; byte j = sign(w[oq*16+(l&15)][(l>>4)*16+j][tap])
  for (int e = tid; e < 2304; e += 512) {
    int oq = e / 576; int rem = e - oq * 576;
    int tap = rem >> 6; int l = rem & 63;
    int o  = oq * 16 + (l & 15);
    int c0 = (l >> 4) * 16;
    unsigned q[4];
    #pragma unroll
    for (int qi = 0; qi < 4; ++qi) {
      unsigned v = 0;
      #pragma unroll
      for (int j = 0; j < 4; ++j) {
        int c = c0 + qi * 4 + j;
        float wv = w_conv[o * 576 + c * 9 + tap];
        unsigned by = (wv > 0.f) ? 0x01u : 0xFFu;
        v |= by << (8 * j);
      }
      q[qi] = v;
    }
    v4i qv; qv.x = (int)q[0]; qv.y = (int)q[1]; qv.z = (int)q[2]; qv.w = (int)q[3];
    *(v4i*)(atab + (size_t)e * 16) = qv;
  }

  {
    float s = sums[tid], s2 = sums[512 + tid], sa = sums[1024 + tid];
    const float invN = 1.f / (float)HW;
    float mean = s * invN;
    float var  = (s2 - s * s * invN) * (1.f / (float)(HW - 1)) + EPSV;
    stA[tid] = sa * invN;
    stM[tid] = mean;
    stS[tid] = sqrtf(var);
  }
  {
    int o = tid >> 3, g = tid & 7;
    const float* wo = w_conv + o * 576 + g * 72;
    float s = 0.f;
    u64 wb[9] = {0,0,0,0,0,0,0,0,0};
    #pragma unroll
    for (int i = 0; i < 8; i++) {
      #pragma unroll
      for (int tp = 0; tp < 9; tp++) {
        float v = wo[i * 9 + tp];
        s += fabsf(v);
        if (v > 0.f) wb[tp] |= (1ull << (g * 8 + i));
      }
    }
    #pragma unroll
    for (int off = 4; off > 0; off >>= 1) {
      s += __shfl_down(s, off, 8);
      #pragma unroll
      for (int tp = 0; tp < 9; tp++)
        wb[tp] |= __shfl_down(wb[tp], off, 8);
    }
    if (g == 0) {
      swv[o] = s * (1.f / 576.f);
      #pragma unroll
      for (int tp = 0; tp < 9; tp++)
        stap[o][tp] = (float)(2 * (int)__popcll(wb[tp]) - 64);
    }
  }
  __syncthreads();
  for (int i = tid; i < 576; i += 512) {
    int cse = i >> 6, o = i & 63;
    int vc = cse / 3, hc = cse - vc * 3;
    int ky0 = (vc == 0) ? 1 : 0, ky1 = (vc == 2) ? 1 : 2;
    int kx0 = (hc == 0) ? 1 : 0, kx1 = (hc == 2) ? 1 : 2;
    float sw = 0.f;
    for (int ky = ky0; ky <= ky1; ++ky)
      for (int kx = kx0; kx <= kx1; ++kx)
        sw += stap[o][ky * 3 + kx];
    sumw_g[cse * 64 + o] = sw;
  }
  int b = tid >> 6, c = tid & 63;
  float y = 0.f;
  #pragma unroll
  for (int k = 0; k < 3; k++) {
    int cc = c + k - 1;
    if (cc >= 0 && cc < 64) {
      int j = b * 64 + cc;
      y += stA[j] * w1d[0 * 3 + k] + stM[j] * w1d[1 * 3 + k] + stS[j] * w1d[2 * 3 + k];
    }
  }
  float gate = 1.f / (1.f + expf(-y));
  alpha[tid] = gate * swv[c];
}

// -------- K3: i8 MFMA 16x16x64 conv: wave = 16 px x 16 o, 9 MFMA ------------
// 32768 blocks: b(8) h(256) pg(16); 4 waves = 4 o-quarters.
__global__ __launch_bounds__(256) void k_convmm(const u64* __restrict__ packed,
                                                const char* __restrict__ atab,
                                                const float* __restrict__ sumw_g,
                                                const float* __restrict__ alpha,
                                                const float* __restrict__ x,
                                                const float* __restrict__ pr_b0,
                                                const float* __restrict__ prelu_a,
                                                const float* __restrict__ pr_b1,
                                                float* __restrict__ out) {
  int blk = blockIdx.x;
  int b  = blk >> 12;
  int h  = (blk >> 4) & 255;
  int pg = blk & 15;
  int tid = threadIdx.x, oq = tid >> 6, lane = tid & 63;
  int n  = lane & 15;
  int kq = lane >> 4;
  int px = pg * 16 + n;

  __shared__ float s_sumw[576];
  __shared__ float s_al[64], s_b0[64], s_pa[64], s_b1[64];
  for (int i = tid; i < 576; i += 256) s_sumw[i] = sumw_g[i];
  if (tid < 64) {
    s_al[tid] = alpha[b * 64 + tid];
    s_b0[tid] = pr_b0[tid]; s_pa[tid] = prelu_a[tid]; s_b1[tid] = pr_b1[tid];
  }
  __syncthreads();

  v4i af[9];
  #pragma unroll
  for (int t9 = 0; t9 < 9; ++t9)
    af[t9] = ((const v4i*)atab)[(oq * 9 + t9) * 64 + lane];

  v4i acc = {0, 0, 0, 0};
  const u64* pb = packed + (size_t)b * HW;
  const unsigned MAGIC = 0x00204081u;
  int sh = kq * 16;

  #pragma unroll
  for (int dy = -1; dy <= 1; ++dy) {
    int hh = h + dy;
    if (hh < 0 || hh > H - 1) continue;          // wave-uniform
    const u64* rp = pb + hh * W;
    #pragma unroll
    for (int dx = 0; dx < 3; ++dx) {
      int wn = px + dx - 1;
      int wc = wn < 0 ? 0 : (wn > W - 1 ? W - 1 : wn);
      u64 mm = rp[wc];
      mm = (wn == wc) ? mm : 0ull;               // zero mask => zero bytes => pad
      unsigned n16 = (unsigned)(mm >> sh) & 0xFFFFu;
      v4i bf;
      bf.x = (int)(((n16        & 0xFu) * MAGIC) & 0x01010101u);
      bf.y = (int)((((n16 >> 4) & 0xFu) * MAGIC) & 0x01010101u);
      bf.z = (int)((((n16 >> 8) & 0xFu) * MAGIC) & 0x01010101u);
      bf.w = (int)((((n16 >>12) & 0xFu) * MAGIC) & 0x01010101u);
      acc = __builtin_amdgcn_mfma_i32_16x16x64_i8(af[(dy + 1) * 3 + dx], bf, acc, 0, 0, 0);
    }
  }

  int vc = (h == 0) ? 0 : ((h == H - 1) ? 2 : 1);
  int hc = (px == 0) ? 0 : ((px == W - 1) ? 2 : 1);
  const float* swrow = s_sumw + (vc * 3 + hc) * 64;
  size_t pxoff = (size_t)b * C * HW + (size_t)h * W + px;

  #pragma unroll
  for (int r = 0; r < 4; ++r) {
    int o = oq * 16 + kq * 4 + r;                // C-layout: col=lane&15, row=(lane>>4)*4+r
    float dot = 2.0f * (float)acc[r] - swrow[o];
    float v = dot * s_al[o] + s_b0[o];
    v = (v > 0.f) ? v : s_pa[o] * v;
    v += s_b1[o] + x[pxoff + (size_t)o * HW];
    __builtin_nontemporal_store(v, out + pxoff + (size_t)o * HW);
  }
}

extern "C" void kernel_launch(void* const* d_in, const int* in_sizes, int n_in,
                              void* d_out, int out_size, void* d_ws, size_t ws_size,
                              hipStream_t stream) {
  const float* x       = (const float*)d_in[0];
  const float* b_move  = (const float*)d_in[1];
  const float* w_conv  = (const float*)d_in[2];
  const float* w1d     = (const float*)d_in[3];
  const float* pr_b0   = (const float*)d_in[4];
  const float* prelu_a = (const float*)d_in[5];
  const float* pr_b1   = (const float*)d_in[6];
  float* out = (float*)d_out;

  char* ws = (char*)d_ws;
  u64*   packed = (u64*)ws;                          // 4 MiB
  float* sums   = (float*)(ws + 4194304);            // 6144 B
  float* alpha  = (float*)(ws + 4194304 + 8192);     // 2048 B
  float* sumw   = (float*)(ws + 4194304 + 24576);    // 2304 B
  char*  atab   =         (ws + 4194304 + 32768);    // 36864 B

  k_sp<<<1536, 256, 0, stream>>>(x, b_move, sums, packed);
  k_gate<<<1, 512, 0, stream>>>(sums, w_conv, w1d, alpha, sumw, atab);
  k_convmm<<<32768, 256, 0, stream>>>(packed, atab, sumw, alpha, x,
                                      pr_b0, prelu_a, pr_b1, out);
}

// Round 15
// 117.758 us; speedup vs baseline: 1.5476x; 1.5476x over previous
//
#include <hip/hip_runtime.h>
#include <stdint.h>

#define BB 8
#define C  64
#define H  256
#define W  256
#define HW (H*W)
#define EPSV 1e-6f

typedef unsigned long long u64;
typedef float __attribute__((ext_vector_type(4))) f32x4;

// ------- K1: fused sign-pack + stats (R6-proven padded LDS transpose) -------
// 1024 blocks (b = blk>>7, 2-row strip rg), 256 threads, 4 tiles of 64ch x 128px.
// Load: coalesced f32x4 -> padded LDS [c][33] (conflict-free, 17.5us proven).
// Consume: lane=channel; register stats accumulate + ballot pack (adds ~1.3us).
__global__ __launch_bounds__(256) void k_packstats(
    const float* __restrict__ x,
    const float* __restrict__ bmove,
    u64* __restrict__ packed,
    float* __restrict__ part /* [512 bc][3 st][128 rg] */) {
  int blk = blockIdx.x;
  int b   = blk >> 7;
  int rg  = blk & 127;
  int h0  = rg << 1;
  int tid = threadIdx.x;
  int wid = tid >> 6, lane = tid & 63;

  __shared__ f32x4 lds4[64 * 33];     // padded: conflict-free write AND read
  __shared__ float sred[4][3][64];

  float bm = bmove[lane];             // lane = channel in consume phase
  float s = 0.f, s2 = 0.f, sa = 0.f;

  int p4l = tid & 31;                 // load phase: f4 chunk within 128px
  int cg  = tid >> 5;                 // load phase: channel sub-group 0..7
  const size_t bbase = (size_t)b * C * HW;

  for (int tile = 0; tile < 4; ++tile) {
    int h  = h0 + (tile >> 1);
    int wb = (tile & 1) << 7;
    __syncthreads();
    #pragma unroll
    for (int cc = 0; cc < 8; ++cc) {
      int c = cg + (cc << 3);
      lds4[c * 33 + p4l] =
          *((const f32x4*)(x + bbase + (size_t)c * HW + h * W + wb) + p4l);
    }
    __syncthreads();
    u64* pdst = packed + ((size_t)(b * H + h)) * W + wb;
    #pragma unroll
    for (int k = 0; k < 8; ++k) {
      int p4i = (wid << 3) + k;
      f32x4 v = lds4[lane * 33 + p4i];
      float a0 = v.x + bm, a1 = v.y + bm, a2 = v.z + bm, a3 = v.w + bm;
      s  += (a0 + a1) + (a2 + a3);
      s2 += a0*a0 + a1*a1 + a2*a2 + a3*a3;
      sa += (fabsf(a0) + fabsf(a1)) + (fabsf(a2) + fabsf(a3));
      u64 q0 = __ballot(a0 > 0.f);
      u64 q1 = __ballot(a1 > 0.f);
      u64 q2 = __ballot(a2 > 0.f);
      u64 q3 = __ballot(a3 > 0.f);
      u64 qa = (lane & 1) ? q1 : q0;
      u64 qb = (lane & 1) ? q3 : q2;
      u64 qq = (lane & 2) ? qb : qa;
      if (lane < 4) pdst[(p4i << 2) + lane] = qq;
    }
  }
  sred[wid][0][lane] = s;
  sred[wid][1][lane] = s2;
  sred[wid][2][lane] = sa;
  __syncthreads();
  if (tid < 192) {
    int st = tid >> 6, c = tid & 63;
    float v = sred[0][st][c] + sred[1][st][c] + sred[2][st][c] + sred[3][st][c];
    part[((size_t)(b * 64 + c) * 3 + st) * 128 + rg] = v;
  }
}

// ---------------- K2: finish stats, gate, weight prep (R8 verbatim) ---------
__global__ __launch_bounds__(512) void k_gate(
    const float* __restrict__ part,
    const float* __restrict__ w_conv,
    const float* __restrict__ w1d,
    float* __restrict__ alpha,
    u64* __restrict__ wsign) {
  __shared__ float stA[512], stM[512], stS[512];  // [b*64 + c]
  __shared__ float swv[64];
  int tid = threadIdx.x;
  {
    const f32x4* p = (const f32x4*)(part + (size_t)tid * 384);
    float s = 0.f, s2 = 0.f, sa = 0.f;
    for (int k = 0;  k < 32; k++) { f32x4 v = p[k]; s  += (v.x + v.y) + (v.z + v.w); }
    for (int k = 32; k < 64; k++) { f32x4 v = p[k]; s2 += (v.x + v.y) + (v.z + v.w); }
    for (int k = 64; k < 96; k++) { f32x4 v = p[k]; sa += (v.x + v.y) + (v.z + v.w); }
    const float invN = 1.f / (float)HW;
    float mean = s * invN;
    float var  = (s2 - s * s * invN) * (1.f / (float)(HW - 1)) + EPSV;
    stA[tid] = sa * invN;
    stM[tid] = mean;
    stS[tid] = sqrtf(var);
  }
  {
    int o = tid >> 3, g = tid & 7;                 // 8 lanes per out-channel
    const float* wo = w_conv + o * 576 + g * 72;   // 8 in-channels x 9 taps
    float s = 0.f;
    u64 wb[9] = {0,0,0,0,0,0,0,0,0};
    #pragma unroll
    for (int i = 0; i < 8; i++) {
      #pragma unroll
      for (int tp = 0; tp < 9; tp++) {
        float v = wo[i * 9 + tp];
        s += fabsf(v);
        if (v > 0.f) wb[tp] |= (1ull << (g * 8 + i));
      }
    }
    #pragma unroll
    for (int off = 4; off > 0; off >>= 1) {
      s += __shfl_down(s, off, 8);
      #pragma unroll
      for (int tp = 0; tp < 9; tp++)
        wb[tp] |= __shfl_down(wb[tp], off, 8);
    }
    if (g == 0) {
      swv[o] = s * (1.f / 576.f);
      #pragma unroll
      for (int tp = 0; tp < 9; tp++) wsign[o * 9 + tp] = wb[tp];
    }
  }
  __syncthreads();
  int b = tid >> 6, c = tid & 63;
  float y = 0.f;
  #pragma unroll
  for (int k = 0; k < 3; k++) {
    int cc = c + k - 1;
    if (cc >= 0 && cc < 64) {
      int j = b * 64 + cc;
      y += stA[j] * w1d[0 * 3 + k] + stM[j] * w1d[1 * 3 + k] + stS[j] * w1d[2 * 3 + k];
    }
  }
  float gate = 1.f / (1.f + expf(-y));
  alpha[tid] = gate * swv[c];   // folds scale_w[o] * gate[b][o]
}

// ---------------- K3: XNOR conv, 4 px/thread, o-split x4 (R13 verbatim) -----
// 2048 blocks: blk = b*256 + hg*4 + oq. Block: 4-row strip, o in [oq*16, +16).
__global__ __launch_bounds__(256) void k_conv4(const u64* __restrict__ packed,
                                               const u64* __restrict__ wsign,
                                               const float* __restrict__ alpha,
                                               const float* __restrict__ x,
                                               const float* __restrict__ pr_b0,
                                               const float* __restrict__ prelu_a,
                                               const float* __restrict__ pr_b1,
                                               float* __restrict__ out) {
  int blk = blockIdx.x;
  int oq = blk & 3;
  int hg = (blk >> 2) & 63;
  int b  = blk >> 8;
  int h0 = hg << 2;
  int t = threadIdx.x;
  __shared__ u64 rows[6][W];          // packed rows h0-1 .. h0+4
  const u64* pb = packed + (size_t)b * H * W;
  #pragma unroll
  for (int r = 0; r < 6; ++r) {
    int hr = h0 - 1 + r;
    rows[r][t] = (hr >= 0 && hr < H) ? pb[hr * W + t] : 0ull;
  }
  __syncthreads();

  int tr = t >> 6, lane = t & 63;
  int tw = lane << 2;
  int h  = h0 + tr;
  bool rTop = (h > 0), rBot = (h < H - 1);       // wave-uniform
  u64 vm0 = (lane == 0)  ? 0ull : ~0ull;
  u64 vm5 = (lane == 63) ? 0ull : ~0ull;

  u64 nw[3][6];
  #pragma unroll
  for (int rr = 0; rr < 3; ++rr) {
    #pragma unroll
    for (int j = 0; j < 6; ++j) {
      int wi = tw - 1 + j;
      wi = (wi < 0) ? 0 : (wi > W - 1 ? W - 1 : wi);
      nw[rr][j] = rows[tr + rr][wi];
    }
  }
  int nr = 1 + (int)rTop + (int)rBot;
  float base0 = 64.f * (float)nr * ((lane == 0)  ? 2.f : 3.f);
  float base1 = 64.f * (float)nr * 3.f;
  float base3 = 64.f * (float)nr * ((lane == 63) ? 2.f : 3.f);

  int o0 = oq << 4;
  size_t xoff = (size_t)b * C * HW + (size_t)(o0) * HW + (size_t)h * W + tw;
  const float* al = alpha + b * 64 + o0;
  const float* pb0 = pr_b0 + o0;
  const float* ppa = prelu_a + o0;
  const float* pb1 = pr_b1 + o0;
  const u64* wsq = wsign + (size_t)o0 * 9;

  #pragma unroll 2
  for (int oo = 0; oo < 16; ++oo) {
    const u64* ws = wsq + oo * 9;
    u64 w0=ws[0], w1=ws[1], w2=ws[2], w3=ws[3], w4=ws[4],
        w5=ws[5], w6=ws[6], w7=ws[7], w8=ws[8];
    f32x4 xr = *(const f32x4*)(x + xoff + (size_t)oo * HW);
    int c0 = 0, c1 = 0, c2 = 0, c3 = 0;
    if (rTop) {
      c0 += __popcll((nw[0][0]^w0)&vm0) + __popcll(nw[0][1]^w1) + __popcll(nw[0][2]^w2);
      c1 += __popcll(nw[0][1]^w0) + __popcll(nw[0][2]^w1) + __popcll(nw[0][3]^w2);
      c2 += __popcll(nw[0][2]^w0) + __popcll(nw[0][3]^w1) + __popcll(nw[0][4]^w2);
      c3 += __popcll(nw[0][3]^w0) + __popcll(nw[0][4]^w1) + __popcll((nw[0][5]^w2)&vm5);
    }
    {
      c0 += __popcll((nw[1][0]^w3)&vm0) + __popcll(nw[1][1]^w4) + __popcll(nw[1][2]^w5);
      c1 += __popcll(nw[1][1]^w3) + __popcll(nw[1][2]^w4) + __popcll(nw[1][3]^w5);
      c2 += __popcll(nw[1][2]^w3) + __popcll(nw[1][3]^w4) + __popcll(nw[1][4]^w5);
      c3 += __popcll(nw[1][3]^w3) + __popcll(nw[1][4]^w4) + __popcll((nw[1][5]^w5)&vm5);
    }
    if (rBot) {
      c0 += __popcll((nw[2][0]^w6)&vm0) + __popcll(nw[2][1]^w7) + __popcll(nw[2][2]^w8);
      c1 += __popcll(nw[2][1]^w6) + __popcll(nw[2][2]^w7) + __popcll(nw[2][3]^w8);
      c2 += __popcll(nw[2][2]^w6) + __popcll(nw[2][3]^w7) + __popcll(nw[2][4]^w8);
      c3 += __popcll(nw[2][3]^w6) + __popcll(nw[2][4]^w7) + __popcll((nw[2][5]^w8)&vm5);
    }
    float a  = al[oo];
    float b0 = pb0[oo], pa = ppa[oo], b1 = pb1[oo];
    float d0 = (base0 - 2.f*(float)c0) * a + b0;
    float d1 = (base1 - 2.f*(float)c1) * a + b0;
    float d2 = (base1 - 2.f*(float)c2) * a + b0;
    float d3 = (base3 - 2.f*(float)c3) * a + b0;
    d0 = (d0 > 0.f) ? d0 : pa * d0;
    d1 = (d1 > 0.f) ? d1 : pa * d1;
    d2 = (d2 > 0.f) ? d2 : pa * d2;
    d3 = (d3 > 0.f) ? d3 : pa * d3;
    f32x4 ov;
    ov.x = d0 + b1 + xr.x;
    ov.y = d1 + b1 + xr.y;
    ov.z = d2 + b1 + xr.z;
    ov.w = d3 + b1 + xr.w;
    __builtin_nontemporal_store(ov, (f32x4*)(out + xoff + (size_t)oo * HW));
  }
}

extern "C" void kernel_launch(void* const* d_in, const int* in_sizes, int n_in,
                              void* d_out, int out_size, void* d_ws, size_t ws_size,
                              hipStream_t stream) {
  const float* x       = (const float*)d_in[0];
  const float* b_move  = (const float*)d_in[1];
  const float* w_conv  = (const float*)d_in[2];
  const float* w1d     = (const float*)d_in[3];
  const float* pr_b0   = (const float*)d_in[4];
  const float* prelu_a = (const float*)d_in[5];
  const float* pr_b1   = (const float*)d_in[6];
  float* out = (float*)d_out;

  char* ws = (char*)d_ws;
  // ws: packed u64[8*256*256] = 4 MiB; part = 512*3*128 f32 (768 KiB);
  // alpha 512 f32; wsign 576 u64
  u64*   packed = (u64*)ws;
  float* part   = (float*)(ws + 4194304);
  float* alpha  = (float*)(ws + 4194304 + 786432);
  u64*   wsign  = (u64*)(ws + 4194304 + 786432 + 4096);

  k_packstats<<<1024, 256, 0, stream>>>(x, b_move, packed, part);
  k_gate<<<1, 512, 0, stream>>>(part, w_conv, w1d, alpha, wsign);
  k_conv4<<<2048, 256, 0, stream>>>(packed, wsign, alpha, x,
                                    pr_b0, prelu_a, pr_b1, out);
}